// Round 7
// baseline (2053.121 us; speedup 1.0000x reference)
//
#include <hip/hip_runtime.h>

constexpr int S    = 256;
constexpr int D    = 32;
constexpr int NH   = 4;
constexpr int DH   = 8;
constexpr int DFF  = 64;
constexpr int NL   = 4;
constexpr int IND  = 58;
constexpr int HOUT = 25;
constexpr int TPB  = 512;  // 1 window/block, 2 threads/token, 8 waves

typedef float  f2 __attribute__((ext_vector_type(2)));
typedef float  f4 __attribute__((ext_vector_type(4)));
typedef __fp16 h2 __attribute__((ext_vector_type(2)));
typedef __fp16 h4 __attribute__((ext_vector_type(4)));
typedef __fp16 h8 __attribute__((ext_vector_type(8)));

// LDS map (bytes), 64 KB total
constexpr int KOFF = 0;      // K A-frags [h4][jt16][qs2][m16]*8B = 16 KB
constexpr int QOFF = 16384;  // Q B-frags, same layout = 16 KB
constexpr int VOFF = 32768;  // V^T 32 rows x 512 B, XOR-swizzled = 16 KB
constexpr int OOFF = 49152;  // attn out [256 tok][32 f16] = 16 KB
constexpr int HOFF = QOFF;   // h exchange f32 [256][32] over Q+V (dead there)

__device__ __forceinline__ unsigned pk2(float a, float b) {
  h2 h = __builtin_amdgcn_cvt_pkrtz(a, b);
  return __builtin_bit_cast(unsigned, h);
}

// packed-fp32 dot (v_pk_fma_f32). All register-array loops must FULLY unroll
// (partial unroll -> scratch demotion, the round-3 251 MB regression).
template<int NF2>
__device__ __forceinline__ float dotp(const float* __restrict__ w,
                                      const float* __restrict__ v) {
  const f2* W = (const f2*)w;
  const f2* V = (const f2*)v;
  f2 a0 = {0.f, 0.f}, a1 = {0.f, 0.f};
#pragma unroll
  for (int i = 0; i < NF2; i += 2) a0 += V[i] * W[i];
#pragma unroll
  for (int i = 1; i < NF2; i += 2) a1 += V[i] * W[i];
  f2 s = a0 + a1;
  return s.x + s.y;
}

// tanh-approx GELU via exp (max dev from exact ~3e-4, below bf16 floor).
__device__ __forceinline__ float gelu(float x) {
  float u = 1.5957691216057308f * fmaf(0.044715f * x * x, x, x);  // 2*sqrt(2/pi)*(x+c x^3)
  return x / (1.0f + __expf(-u));
}

__device__ __forceinline__ void lnorm(float* h, const float* __restrict__ g,
                                      const float* __restrict__ b) {
  float s = 0.f;
#pragma unroll
  for (int d = 0; d < D; ++d) s += h[d];
  const float m = s * (1.0f / D);
  float v = 0.f;
#pragma unroll
  for (int d = 0; d < D; ++d) { float c = h[d] - m; v = fmaf(c, c, v); }
  const float inv = rsqrtf(v * (1.0f / D) + 1e-5f);
#pragma unroll
  for (int d = 0; d < D; ++d) h[d] = (h[d] - m) * inv * g[d] + b[d];
}

__device__ __forceinline__ void embed_token(
    const float* __restrict__ xrow, int lay,
    const float* __restrict__ fpw, const float* __restrict__ fpb,
    const float* __restrict__ lemb, const float* __restrict__ fB,
    float* __restrict__ h) {
  float xr[IND];
  const f2* xv = (const f2*)xrow;  // row stride 232 B -> 8-B aligned
#pragma unroll
  for (int i = 0; i < 29; ++i) { f2 t = xv[i]; xr[2 * i] = t.x; xr[2 * i + 1] = t.y; }
  const float* le = lemb + lay * D;
  float pe[D];
#pragma unroll
  for (int k = 0; k < 16; ++k) {
    float pr = 6.2831853071795864f *
               (xr[0] * fB[k] + xr[1] * fB[16 + k] + xr[2] * fB[32 + k]);
    float sv, cv;
    sincosf(pr, &sv, &cv);
    pe[k] = sv; pe[16 + k] = cv;
  }
#pragma unroll
  for (int d = 0; d < D; ++d)
    h[d] = dotp<29>(fpw + d * IND, xr) + fpb[d] + le[d] + pe[d];
}

__device__ __forceinline__ void post_token(
    int l, float* __restrict__ h, const float* __restrict__ acc,
    const float* __restrict__ opw, const float* __restrict__ opb,
    const float* __restrict__ ln1g, const float* __restrict__ ln1b,
    const float* __restrict__ w1, const float* __restrict__ b1,
    const float* __restrict__ w2, const float* __restrict__ b2,
    const float* __restrict__ ln2g, const float* __restrict__ ln2b) {
  const float* Wo = opw + l * D * D;
  const float* Bo = opb + l * D;
#pragma unroll
  for (int o = 0; o < D; ++o) h[o] += dotp<16>(Wo + o * D, acc) + Bo[o];
  lnorm(h, ln1g + l * D, ln1b + l * D);
  const float* Wa = w1 + l * DFF * D;
  const float* Ba = b1 + l * DFF;
  float tt[DFF];
#pragma unroll
  for (int j = 0; j < DFF; ++j)
    tt[j] = gelu(dotp<16>(Wa + j * D, h) + Ba[j]);
  const float* Wb = w2 + l * D * DFF;
  const float* Bb = b2 + l * D;
#pragma unroll
  for (int d = 0; d < D; ++d) h[d] += dotp<32>(Wb + d * DFF, tt) + Bb[d];
  lnorm(h, ln2g + l * D, ln2b + l * D);
}

// launch_bounds(512,3): VGPR cap ~170 -- round 6's (512,4) cap of 128 forced
// VGPR=64 + ~690 MB scratch spill traffic. Natural footprint is ~128-160.
__global__ void __launch_bounds__(TPB, 3)
spai_fused(const float* __restrict__ x,    const int*   __restrict__ layers,
           const float* __restrict__ fpw,  const float* __restrict__ fpb,
           const float* __restrict__ lemb, const float* __restrict__ fB,
           const float* __restrict__ ipw,  const float* __restrict__ ipb,
           const float* __restrict__ opw,  const float* __restrict__ opb,
           const float* __restrict__ ln1g, const float* __restrict__ ln1b,
           const float* __restrict__ w1,   const float* __restrict__ b1,
           const float* __restrict__ w2,   const float* __restrict__ b2,
           const float* __restrict__ ln2g, const float* __restrict__ ln2b,
           const float* __restrict__ nog,  const float* __restrict__ nob,
           const float* __restrict__ hw,   const float* __restrict__ hb,
           float* __restrict__ out) {
  __shared__ __align__(16) unsigned char sm[65536];
  const int tid  = threadIdx.x;
  const int tok  = tid & 255;
  const int half = tid >> 8;        // wave-uniform (waves 0-3: half 0)
  const size_t blk_tok = (size_t)blockIdx.x * S;
  const int hsw = (tok & 7) * 16;   // h-exchange chunk swizzle (bytes)

  float h[D];
  if (half == 0) {
    embed_token(x + (blk_tok + tok) * IND, layers[blk_tok + tok],
                fpw, fpb, lemb, fB, h);
#pragma unroll
    for (int k = 0; k < 8; ++k)
      *(f4*)(sm + HOFF + tok * 128 + ((k * 16) ^ hsw)) = *(const f4*)(h + 4 * k);
  }
  __syncthreads();

  const int it_w = tok >> 4;
  const int m_w  = tok & 15;

  for (int l = 0; l < NL; ++l) {
    const float* Wi = ipw + l * (3 * D) * D;
    const float* Bi = ipb + l * (3 * D);

    // ---------- phase 1: QKV (2 heads per thread) ----------
    if (half) {
#pragma unroll
      for (int k = 0; k < 8; ++k)
        *(f4*)(h + 4 * k) = *(const f4*)(sm + HOFF + tok * 128 + ((k * 16) ^ hsw));
    }
    __syncthreads();  // h reads done before frag writes clobber Q/V regions
#pragma unroll
    for (int hi = 0; hi < 2; ++hi) {
      const int hd = 2 * half + hi;  // wave-uniform -> s_load weights
      float qv[8], kv[8];
#pragma unroll
      for (int e = 0; e < 8; ++e)
        qv[e] = (dotp<16>(Wi + (hd * 8 + e) * D, h) + Bi[hd * 8 + e]) *
                0.35355339059327373f;  // fold 1/sqrt(dh)
#pragma unroll
      for (int e = 0; e < 8; ++e)
        kv[e] = dotp<16>(Wi + (D + hd * 8 + e) * D, h) + Bi[D + hd * 8 + e];
      const int fbase = ((hd * 16 + it_w) * 32 + m_w) * 8;
      *(uint2*)(sm + QOFF + fbase)       = uint2{pk2(qv[0], qv[1]), pk2(qv[2], qv[3])};
      *(uint2*)(sm + QOFF + fbase + 128) = uint2{pk2(qv[4], qv[5]), pk2(qv[6], qv[7])};
      *(uint2*)(sm + KOFF + fbase)       = uint2{pk2(kv[0], kv[1]), pk2(kv[2], kv[3])};
      *(uint2*)(sm + KOFF + fbase + 128) = uint2{pk2(kv[4], kv[5]), pk2(kv[6], kv[7])};
#pragma unroll
      for (int e = 0; e < 8; ++e) {
        float vv = dotp<16>(Wi + (2 * D + hd * 8 + e) * D, h) + Bi[2 * D + hd * 8 + e];
        const int c = ((tok >> 2) ^ (e << 1)) * 8 + (tok & 3) * 2;
        *(__fp16*)(sm + VOFF + (hd * 8 + e) * 512 + c) = (__fp16)vv;
      }
    }
    __syncthreads();

    // ---------- phase 2: flash attention, wave = (head, it-half) ----------
    {
      const int lane = tid & 63;
      const int wave = tid >> 6;
      const int hh   = wave & 3;
      const int itb  = (wave >> 2) * 8;
      const int m    = lane & 15;
      const int quad = lane >> 4;
      const int qs   = quad & 1;

      h4 Af[16];  // K A-frags, it-invariant; quads 2,3 = dh 8->16 zero pad
#pragma unroll
      for (int jt = 0; jt < 16; ++jt) {
        uint2 a = *(const uint2*)(sm + KOFF + ((hh * 16 + jt) * 32 + qs * 16 + m) * 8);
        if (quad >= 2) { a.x = 0u; a.y = 0u; }
        Af[jt] = __builtin_bit_cast(h4, a);
      }
      const int vbase = VOFF + (hh * 8 + (m & 7)) * 512;
      const int vkey  = (m & 7) << 1;

#pragma unroll 2
      for (int ii = 0; ii < 8; ++ii) {
        const int it = itb + ii;
        h4 Qf = *(const h4*)(sm + QOFF + ((hh * 16 + it) * 32 + qs * 16 + m) * 8);
        f4 Of = {0.f, 0.f, 0.f, 0.f};
        float lsum = 0.f;
#pragma unroll
        for (int jt = 0; jt < 16; ++jt) {
          // T[j,i] = K·Q^T: C col = i (lane&15), row = j (quad*4+r)
          f4 T = __builtin_amdgcn_mfma_f32_16x16x16f16(
                     Af[jt], Qf, (f4){0.f, 0.f, 0.f, 0.f}, 0, 0, 0);
          float e0 = __expf(T[0]), e1 = __expf(T[1]);
          float e2 = __expf(T[2]), e3 = __expf(T[3]);
          lsum += (e0 + e1) + (e2 + e3);
          uint2 pu{pk2(e0, e1), pk2(e2, e3)};
          h4 P = __builtin_bit_cast(h4, pu);  // C-frag of T == A-frag of P
          h4 Bv = *(const h4*)(sm + vbase + (((jt * 4 + quad) ^ vkey) * 8));
          Of = __builtin_amdgcn_mfma_f32_16x16x16f16(P, Bv, Of, 0, 0, 0);
        }
        lsum += __shfl_xor(lsum, 16);
        lsum += __shfl_xor(lsum, 32);  // every lane: lsum of query i = lane&15
#pragma unroll
        for (int r = 0; r < 4; ++r) {
          float ls = __builtin_bit_cast(
              float, __builtin_amdgcn_ds_bpermute(
                         (quad * 4 + r) << 2, __builtin_bit_cast(int, lsum)));
          float o = Of[r] * __builtin_amdgcn_rcpf(ls);
          if (m < 8) {
            const int t2 = it * 16 + quad * 4 + r;
            *(__fp16*)(sm + OOFF + t2 * 64 + (hh * 8 + m) * 2) = (__fp16)o;
          }
        }
      }
    }
    __syncthreads();

    // ---------- phase 3: out-proj + LN + FF + LN (token threads only) ----------
    if (half == 0) {
      float acc[D];
      const uint4* orow = (const uint4*)(sm + OOFF + tok * 64);
#pragma unroll
      for (int c = 0; c < 4; ++c) {
        h8 v8 = __builtin_bit_cast(h8, orow[c]);
#pragma unroll
        for (int e = 0; e < 8; ++e) acc[c * 8 + e] = (float)v8[e];
      }
      post_token(l, h, acc, opw, opb, ln1g, ln1b, w1, b1, w2, b2, ln2g, ln2b);
      if (l != NL - 1) {  // last layer: skip (would race final staging region)
#pragma unroll
        for (int k = 0; k < 8; ++k)
          *(f4*)(sm + HOFF + tok * 128 + ((k * 16) ^ hsw)) = *(const f4*)(h + 4 * k);
      }
    }
    __syncthreads();
  }

  // ---------- final LN + head ----------
  if (half == 0) {
    lnorm(h, nog, nob);
    float* hs = (float*)sm;  // 25.6 KB over K + dead h-exchange region
#pragma unroll
    for (int o = 0; o < HOUT; ++o)
      hs[tok * HOUT + o] = dotp<16>(hw + o * D, h) + hb[o];
  }
  __syncthreads();
  f2* og = (f2*)(out + blk_tok * HOUT);
  const f2* os2 = (const f2*)sm;
  for (int i = tid; i < S * HOUT / 2; i += TPB) og[i] = os2[i];
}

extern "C" void kernel_launch(void* const* d_in, const int* in_sizes, int n_in,
                              void* d_out, int out_size, void* d_ws, size_t ws_size,
                              hipStream_t stream) {
  const float* x    = (const float*)d_in[0];
  const int*   lays = (const int*)  d_in[1];
  const float* fpw  = (const float*)d_in[2];
  const float* fpb  = (const float*)d_in[3];
  const float* lemb = (const float*)d_in[4];
  const float* fB   = (const float*)d_in[5];
  const float* ipw  = (const float*)d_in[6];
  const float* ipb  = (const float*)d_in[7];
  const float* opw  = (const float*)d_in[8];
  const float* opb  = (const float*)d_in[9];
  const float* ln1g = (const float*)d_in[10];
  const float* ln1b = (const float*)d_in[11];
  const float* w1   = (const float*)d_in[12];
  const float* b1   = (const float*)d_in[13];
  const float* w2   = (const float*)d_in[14];
  const float* b2   = (const float*)d_in[15];
  const float* ln2g = (const float*)d_in[16];
  const float* ln2b = (const float*)d_in[17];
  const float* nog  = (const float*)d_in[18];
  const float* nob  = (const float*)d_in[19];
  const float* hw   = (const float*)d_in[20];
  const float* hb   = (const float*)d_in[21];
  float* out = (float*)d_out;

  const int nwin = in_sizes[0] / (S * IND);  // 512 windows
  spai_fused<<<nwin, TPB, 0, stream>>>(x, lays, fpw, fpb, lemb, fB, ipw, ipb,
                                       opw, opb, ln1g, ln1b, w1, b1, w2, b2,
                                       ln2g, ln2b, nog, nob, hw, hb, out);
}

// Round 8
// 403.810 us; speedup vs baseline: 5.0844x; 5.0844x over previous
//
#include <hip/hip_runtime.h>

constexpr int S    = 256;
constexpr int D    = 32;
constexpr int NH   = 4;
constexpr int DH   = 8;
constexpr int DFF  = 64;
constexpr int NL   = 4;
constexpr int IND  = 58;
constexpr int HOUT = 25;
constexpr int TPB  = 256;  // 1 window/block, 1 token/thread, 4 waves

typedef float  f2 __attribute__((ext_vector_type(2)));
typedef float  f4 __attribute__((ext_vector_type(4)));
typedef __fp16 h2 __attribute__((ext_vector_type(2)));
typedef __fp16 h4 __attribute__((ext_vector_type(4)));
typedef __fp16 h8 __attribute__((ext_vector_type(8)));

// LDS map (bytes), 64 KB total
constexpr int HOFF  = 0;      // h f16 [256][32] swizzled 8B-chunks; O reuses plain
constexpr int QKOFF = 16384;  // Q|K f16 [256 tok][64 feat], 16B-chunk XOR swizzle
constexpr int VOFF  = 49152;  // V^T 32 rows x 512 B, XOR-swizzled (round-5 layout)

__device__ __forceinline__ unsigned pk2(float a, float b) {
  h2 h = __builtin_amdgcn_cvt_pkrtz(a, b);
  return __builtin_bit_cast(unsigned, h);
}

// packed-fp32 dot (v_pk_fma_f32). All register-array loops must FULLY unroll
// (partial unroll -> scratch demotion, the round-3 251 MB regression).
template<int NF2>
__device__ __forceinline__ float dotp(const float* __restrict__ w,
                                      const float* __restrict__ v) {
  const f2* W = (const f2*)w;
  const f2* V = (const f2*)v;
  f2 a0 = {0.f, 0.f}, a1 = {0.f, 0.f};
#pragma unroll
  for (int i = 0; i < NF2; i += 2) a0 += V[i] * W[i];
#pragma unroll
  for (int i = 1; i < NF2; i += 2) a1 += V[i] * W[i];
  f2 s = a0 + a1;
  return s.x + s.y;
}

// tanh-approx GELU via exp (max dev ~3e-4, below bf16 floor; verified r7 absmax)
__device__ __forceinline__ float gelu(float x) {
  float u = 1.5957691216057308f * fmaf(0.044715f * x * x, x, x);
  return x / (1.0f + __expf(-u));
}

__device__ __forceinline__ void lnorm(float* h, const float* __restrict__ g,
                                      const float* __restrict__ b) {
  float s = 0.f;
#pragma unroll
  for (int d = 0; d < D; ++d) s += h[d];
  const float m = s * (1.0f / D);
  float v = 0.f;
#pragma unroll
  for (int d = 0; d < D; ++d) { float c = h[d] - m; v = fmaf(c, c, v); }
  const float inv = rsqrtf(v * (1.0f / D) + 1e-5f);
#pragma unroll
  for (int d = 0; d < D; ++d) h[d] = (h[d] - m) * inv * g[d] + b[d];
}

__device__ __forceinline__ void embed_token(
    const float* __restrict__ xrow, int lay,
    const float* __restrict__ fpw, const float* __restrict__ fpb,
    const float* __restrict__ lemb, const float* __restrict__ fB,
    float* __restrict__ h) {
  float xr[IND];
  const f2* xv = (const f2*)xrow;
#pragma unroll
  for (int i = 0; i < 29; ++i) { f2 t = xv[i]; xr[2 * i] = t.x; xr[2 * i + 1] = t.y; }
  const float* le = lemb + lay * D;
  float pe[D];
#pragma unroll
  for (int k = 0; k < 16; ++k) {
    float pr = 6.2831853071795864f *
               (xr[0] * fB[k] + xr[1] * fB[16 + k] + xr[2] * fB[32 + k]);
    float sv, cv;
    sincosf(pr, &sv, &cv);
    pe[k] = sv; pe[16 + k] = cv;
  }
#pragma unroll
  for (int d = 0; d < D; ++d)
    h[d] = dotp<29>(fpw + d * IND, xr) + fpb[d] + le[d] + pe[d];
}

__device__ __forceinline__ void post_token(
    int l, float* __restrict__ h, const float* __restrict__ acc,
    const float* __restrict__ opw, const float* __restrict__ opb,
    const float* __restrict__ ln1g, const float* __restrict__ ln1b,
    const float* __restrict__ w1, const float* __restrict__ b1,
    const float* __restrict__ w2, const float* __restrict__ b2,
    const float* __restrict__ ln2g, const float* __restrict__ ln2b) {
  const float* Wo = opw + l * D * D;
  const float* Bo = opb + l * D;
#pragma unroll
  for (int o = 0; o < D; ++o) h[o] += dotp<16>(Wo + o * D, acc) + Bo[o];
  lnorm(h, ln1g + l * D, ln1b + l * D);
  const float* Wa = w1 + l * DFF * D;
  const float* Ba = b1 + l * DFF;
  float tt[DFF];
#pragma unroll
  for (int j = 0; j < DFF; ++j)
    tt[j] = gelu(dotp<16>(Wa + j * D, h) + Ba[j]);
  const float* Wb = w2 + l * D * DFF;
  const float* Bb = b2 + l * D;
#pragma unroll
  for (int d = 0; d < D; ++d) h[d] += dotp<32>(Wb + d * DFF, tt) + Bb[d];
  lnorm(h, ln2g + l * D, ln2b + l * D);
}

// Write this thread's h (f32 regs) as swizzled f16 row into HOFF.
__device__ __forceinline__ void store_h16(unsigned char* sm, int tok,
                                          const float* __restrict__ h) {
#pragma unroll
  for (int c = 0; c < 8; ++c) {
    uint2 p{pk2(h[4 * c], h[4 * c + 1]), pk2(h[4 * c + 2], h[4 * c + 3])};
    *(uint2*)(sm + HOFF + tok * 64 + ((c ^ (tok & 7)) * 8)) = p;
  }
}

__global__ void __launch_bounds__(TPB, 2)
spai_fused(const float* __restrict__ x,    const int*   __restrict__ layers,
           const float* __restrict__ fpw,  const float* __restrict__ fpb,
           const float* __restrict__ lemb, const float* __restrict__ fB,
           const float* __restrict__ ipw,  const float* __restrict__ ipb,
           const float* __restrict__ opw,  const float* __restrict__ opb,
           const float* __restrict__ ln1g, const float* __restrict__ ln1b,
           const float* __restrict__ w1,   const float* __restrict__ b1,
           const float* __restrict__ w2,   const float* __restrict__ b2,
           const float* __restrict__ ln2g, const float* __restrict__ ln2b,
           const float* __restrict__ nog,  const float* __restrict__ nob,
           const float* __restrict__ hw,   const float* __restrict__ hb,
           float* __restrict__ out) {
  __shared__ __align__(16) unsigned char sm[65536];
  const int tid  = threadIdx.x;
  const int lane = tid & 63;
  const int wave = tid >> 6;
  const int n16  = lane & 15;
  const int quad = lane >> 4;
  const int qs   = quad & 1;
  const size_t blk_tok = (size_t)blockIdx.x * S;

  float h[D];
  embed_token(x + (blk_tok + tid) * IND, layers[blk_tok + tid],
              fpw, fpb, lemb, fB, h);
  store_h16(sm, tid, h);
  __syncthreads();

  for (int l = 0; l < NL; ++l) {
    const float* Wi = ipw + l * (3 * D) * D;
    const float* Bi = ipb + l * (3 * D);

    // ---------- phase 1: QKV GEMM via MFMA (wave w -> token tiles w*4..+4) ----
    {
      h4 Bf[12]; float bias[6];
#pragma unroll
      for (int nt = 0; nt < 6; ++nt) {
        const float sc = (nt < 2) ? 0.35355339059327373f : 1.0f;  // fold 1/sqrt(dh)
        bias[nt] = Bi[nt * 16 + n16] * sc;
#pragma unroll
        for (int kh = 0; kh < 2; ++kh) {
          f4 wv = *(const f4*)(Wi + (nt * 16 + n16) * D + kh * 16 + quad * 4) * sc;
          uint2 wp{pk2(wv.x, wv.y), pk2(wv.z, wv.w)};
          Bf[nt * 2 + kh] = __builtin_bit_cast(h4, wp);
        }
      }
      h4 Ah[8];
#pragma unroll
      for (int it = 0; it < 4; ++it) {
        const int tok = (wave * 4 + it) * 16 + n16;
#pragma unroll
        for (int kh = 0; kh < 2; ++kh)
          Ah[it * 2 + kh] =
              *(const h4*)(sm + HOFF + tok * 64 + (((kh * 4 + quad) ^ (tok & 7)) * 8));
      }
#pragma unroll
      for (int it = 0; it < 4; ++it) {
        const int tokb = (wave * 4 + it) * 16 + quad * 4;
#pragma unroll
        for (int nt = 0; nt < 6; ++nt) {
          f4 C = __builtin_amdgcn_mfma_f32_16x16x16f16(
                     Ah[it * 2], Bf[nt * 2], (f4){0.f, 0.f, 0.f, 0.f}, 0, 0, 0);
          C = __builtin_amdgcn_mfma_f32_16x16x16f16(
                  Ah[it * 2 + 1], Bf[nt * 2 + 1], C, 0, 0, 0);
          const int feat = nt * 16 + n16;
#pragma unroll
          for (int r = 0; r < 4; ++r) {
            const int tok = tokb + r;
            __fp16 vh = (__fp16)(C[r] + bias[nt]);
            if (nt < 4) {  // Q (0..31) | K (32..63) -> QK buffer
              *(__fp16*)(sm + QKOFF + tok * 128 +
                         (((feat >> 3) ^ (tok & 7)) * 16) + (feat & 7) * 2) = vh;
            } else {       // V -> V^T (round-5 layout)
              const int vf = feat - 64;
              *(__fp16*)(sm + VOFF + vf * 512 +
                         ((tok >> 2) ^ ((vf & 7) << 1)) * 8 + (tok & 3) * 2) = vh;
            }
          }
        }
      }
    }
    __syncthreads();

    // ---------- phase 2: flash attention (wave = head), as round 5 ----------
    {
      const int hh = wave;
      const int m  = n16;

      h4 Af[16];  // K A-frags; quads 2,3 = dh 8->16 zero pad
#pragma unroll
      for (int jt = 0; jt < 16; ++jt) {
        const int tok = jt * 16 + m;
        uint2 a = *(const uint2*)(sm + QKOFF + tok * 128 +
                                  (((4 + hh) ^ (tok & 7)) * 16) + qs * 8);
        if (quad >= 2) { a.x = 0u; a.y = 0u; }
        Af[jt] = __builtin_bit_cast(h4, a);
      }
      const int vbase = VOFF + (hh * 8 + (m & 7)) * 512;
      const int vkey  = (m & 7) << 1;

#pragma unroll 2
      for (int it = 0; it < 16; ++it) {
        const int ti = it * 16 + m;
        h4 Qf = *(const h4*)(sm + QKOFF + ti * 128 +
                             ((hh ^ (ti & 7)) * 16) + qs * 8);
        f4 Of = {0.f, 0.f, 0.f, 0.f};
        float lsum = 0.f;
#pragma unroll
        for (int jt = 0; jt < 16; ++jt) {
          f4 T = __builtin_amdgcn_mfma_f32_16x16x16f16(
                     Af[jt], Qf, (f4){0.f, 0.f, 0.f, 0.f}, 0, 0, 0);
          float e0 = __expf(T[0]), e1 = __expf(T[1]);
          float e2 = __expf(T[2]), e3 = __expf(T[3]);
          lsum += (e0 + e1) + (e2 + e3);
          uint2 pu{pk2(e0, e1), pk2(e2, e3)};
          h4 P = __builtin_bit_cast(h4, pu);  // C-frag of T == A-frag of P
          h4 Bv = *(const h4*)(sm + vbase + (((jt * 4 + quad) ^ vkey) * 8));
          Of = __builtin_amdgcn_mfma_f32_16x16x16f16(P, Bv, Of, 0, 0, 0);
        }
        lsum += __shfl_xor(lsum, 16);
        lsum += __shfl_xor(lsum, 32);
#pragma unroll
        for (int r = 0; r < 4; ++r) {
          float ls = __builtin_bit_cast(
              float, __builtin_amdgcn_ds_bpermute(
                         (quad * 4 + r) << 2, __builtin_bit_cast(int, lsum)));
          float o = Of[r] * __builtin_amdgcn_rcpf(ls);
          if (m < 8) {  // O -> plain [tok][32 f16] over dead h-f16 region
            const int t2 = it * 16 + quad * 4 + r;
            *(__fp16*)(sm + HOFF + t2 * 64 + (hh * 8 + m) * 2) = (__fp16)o;
          }
        }
      }
    }
    __syncthreads();

    // ---------- phase 3: out-proj + LN + FF + LN (token = thread) ----------
    {
      float acc[D];
      const uint4* orow = (const uint4*)(sm + HOFF + tid * 64);
#pragma unroll
      for (int c = 0; c < 4; ++c) {
        h8 v8 = __builtin_bit_cast(h8, orow[c]);
#pragma unroll
        for (int e = 0; e < 8; ++e) acc[c * 8 + e] = (float)v8[e];
      }
      post_token(l, h, acc, opw, opb, ln1g, ln1b, w1, b1, w2, b2, ln2g, ln2b);
      if (l != NL - 1) store_h16(sm, tid, h);  // own row: no cross-thread race
    }
    __syncthreads();
  }

  // ---------- final LN + head ----------
  lnorm(h, nog, nob);
  float* hs = (float*)sm;  // 25.6 KB staging over dead H/QK regions
#pragma unroll
  for (int o = 0; o < HOUT; ++o)
    hs[tid * HOUT + o] = dotp<16>(hw + o * D, h) + hb[o];
  __syncthreads();
  f2* og = (f2*)(out + blk_tok * HOUT);
  const f2* os2 = (const f2*)hs;
  for (int i = tid; i < S * HOUT / 2; i += TPB) og[i] = os2[i];
}

extern "C" void kernel_launch(void* const* d_in, const int* in_sizes, int n_in,
                              void* d_out, int out_size, void* d_ws, size_t ws_size,
                              hipStream_t stream) {
  const float* x    = (const float*)d_in[0];
  const int*   lays = (const int*)  d_in[1];
  const float* fpw  = (const float*)d_in[2];
  const float* fpb  = (const float*)d_in[3];
  const float* lemb = (const float*)d_in[4];
  const float* fB   = (const float*)d_in[5];
  const float* ipw  = (const float*)d_in[6];
  const float* ipb  = (const float*)d_in[7];
  const float* opw  = (const float*)d_in[8];
  const float* opb  = (const float*)d_in[9];
  const float* ln1g = (const float*)d_in[10];
  const float* ln1b = (const float*)d_in[11];
  const float* w1   = (const float*)d_in[12];
  const float* b1   = (const float*)d_in[13];
  const float* w2   = (const float*)d_in[14];
  const float* b2   = (const float*)d_in[15];
  const float* ln2g = (const float*)d_in[16];
  const float* ln2b = (const float*)d_in[17];
  const float* nog  = (const float*)d_in[18];
  const float* nob  = (const float*)d_in[19];
  const float* hw   = (const float*)d_in[20];
  const float* hb   = (const float*)d_in[21];
  float* out = (float*)d_out;

  const int nwin = in_sizes[0] / (S * IND);  // 512 windows
  spai_fused<<<nwin, TPB, 0, stream>>>(x, lays, fpw, fpb, lemb, fB, ipw, ipb,
                                       opw, opb, ln1g, ln1b, w1, b1, w2, b2,
                                       ln2g, ln2b, nog, nob, hw, hb, out);
}